// Round 1
// baseline (499.343 us; speedup 1.0000x reference)
//
#include <hip/hip_runtime.h>
#include <math.h>

// LSTM B=8192,T=512,IN=3,H=32,OUT=2 fp32.
// R9: 4 batches/wave, 4-fold column replication (cols 4b+qt, qt=0..3 all hold
// batch b) -> 2048 waves = 2 per SIMD: partner wave hides MFMA block time
// (MFMA blocks its wave) + trans/DPP latency that 1-wave/SIMD R8 exposed.
// Quad = the 4 replica lanes of one batch -> B rebuild is 8 v_mov_b32_dpp
// quad-broadcasts (no ds_swizzle, no assembly cndmask, zero LDS).
// x-preacts ride the MFMA C operand ({xp0,xp1,xp0,xp1} covers both element-
// pair read positions; unread slots garbage). Gate math in f32x2 to form
// v_pk_*_f32. 24 MFMA/step/wave, 16 trans/step/wave (2 units/lane).
// P-select: chunk by qt>>1, element-pair by qt&1 (24 cndmask).
// Ping-pong unroll-2: XP(t+1) computed from held x(t+1), prefetch x(t+2).

namespace {
constexpr int   kT   = 512;
constexpr float kL2E = 1.44269504088896340736f;
}

typedef __bf16 bf16x8 __attribute__((ext_vector_type(8)));
typedef float  f32x4  __attribute__((ext_vector_type(4)));
typedef float  f32x2  __attribute__((ext_vector_type(2)));

union Frag {
    bf16x8 v;
    unsigned short u[8];
    unsigned int   d[4];
};

__device__ __forceinline__ unsigned short bf_rne(float f) {
    unsigned u = __float_as_uint(f);
    u += 0x7fffu + ((u >> 16) & 1u);
    return (unsigned short)(u >> 16);
}
__device__ __forceinline__ float bf_tof(unsigned short h) {
    return __uint_as_float((unsigned)h << 16);
}
__device__ __forceinline__ float fast_exp2(float v) { return __builtin_amdgcn_exp2f(v); }
__device__ __forceinline__ float fast_rcp(float v)  { return __builtin_amdgcn_rcpf(v); }

// pack the high-16 bits (bf16 truncation) of two fp32 into one dword:
// result = [lo16 = a.hi16, hi16 = b.hi16]
__device__ __forceinline__ unsigned pack_hi16(float a, float b) {
    return __builtin_amdgcn_perm(__float_as_uint(b), __float_as_uint(a), 0x07060302u);
}

// DPP quad_perm broadcast of quad-lane J to all 4 lanes of the quad.
template <int CTRL>
__device__ __forceinline__ unsigned qb(unsigned v) {
    return (unsigned)__builtin_amdgcn_mov_dpp((int)v, CTRL, 0xF, 0xF, true);
}

__device__ __forceinline__ f32x2 fma2(f32x2 a, f32x2 b, f32x2 c) {
    return __builtin_elementwise_fma(a, b, c);
}
__device__ __forceinline__ f32x2 sp2(float v) {
    f32x2 r = {v, v};
    return r;
}

#define MFMA16 __builtin_amdgcn_mfma_f32_16x16x32_bf16

extern "C" __global__ __launch_bounds__(64, 2)
void lstm_rep4(const float* __restrict__ x,
               const float* __restrict__ W_ih,
               const float* __restrict__ W_hh,
               const float* __restrict__ b_ih,
               const float* __restrict__ b_hh,
               const float* __restrict__ W_fc,
               const float* __restrict__ b_fc,
               float* __restrict__ out) {
    const int  lane = threadIdx.x & 63;
    const int  n    = lane & 15;        // B/D column == A row
    const int  q    = lane >> 4;        // quad-of-k / row group
    const int  qt   = n & 3;            // replica quarter (lane position in quad)
    const int  bat  = n >> 2;           // batch within wave (0..3)
    const int  b    = blockIdx.x * 4 + bat;
    const bool selC = (qt & 2) != 0;    // chunk (pc) select
    const bool selE = (qt & 1) != 0;    // element-pair select

    // ---- A-frags: permuted scaled W_hh (hi/lo) ----
    // chunk cc (g=cc>>1, pc=cc&1): A row m holds W row
    // R = 32g + 8(m>>2) + 4pc + (m&3)  =>  D row 4q+r of chunk cc is
    // gate g, unit u = 8q + 4pc + r (verified R3/R5; unchanged by col pairing).
    Frag Ah[8], Al[8];
#pragma unroll
    for (int cc = 0; cc < 8; ++cc) {
        const int   g  = cc >> 1, pc = cc & 1;
        const float s  = (g == 2) ? -2.0f * kL2E : -kL2E;
        const int   R  = 32 * g + 8 * (n >> 2) + 4 * pc + (n & 3);
#pragma unroll
        for (int j = 0; j < 8; ++j) {
            const float w = W_hh[R * 32 + 8 * q + j] * s;
            const unsigned short hb = bf_rne(w);
            Ah[cc].u[j] = hb;
            Al[cc].u[j] = bf_rne(w - bf_tof(hb));
        }
    }

    // ---- per-lane x-path constants for my 2 units (u0, u0+1) x 4 gates ----
    const int u0 = 8 * q + 2 * qt;
    f32x2 xw[4][3], xbias[4];
#pragma unroll
    for (int g = 0; g < 4; ++g) {
        const float s  = (g == 2) ? -2.0f * kL2E : -kL2E;
        const int   R0 = 32 * g + u0, R1 = R0 + 1;
#pragma unroll
        for (int k = 0; k < 3; ++k) {
            f32x2 w = {W_ih[R0 * 3 + k] * s, W_ih[R1 * 3 + k] * s};
            xw[g][k] = w;
        }
        f32x2 bb = {(b_ih[R0] + b_hh[R0]) * s, (b_ih[R1] + b_hh[R1]) * s};
        xbias[g] = bb;
    }

    const float* xb = x + (size_t)b * kT * 3;

    f32x2 cst = {0.f, 0.f};
    f32x2 h2  = {0.f, 0.f};
    Frag Bh, Bl;
#pragma unroll
    for (int j = 0; j < 4; ++j) { Bh.d[j] = 0; Bl.d[j] = 0; }

    // ---- pipeline prologue: XPa = XP(0) from x[0]; U = x(1) ----
    f32x4 XPa[4], XPb[4];
    {
        const float a0 = xb[0], a1 = xb[1], a2 = xb[2];
#pragma unroll
        for (int g = 0; g < 4; ++g) {
            f32x2 p = fma2(sp2(a0), xw[g][0],
                      fma2(sp2(a1), xw[g][1],
                      fma2(sp2(a2), xw[g][2], xbias[g])));
            f32x4 t4 = {p.x, p.y, p.x, p.y};  // correct for both selE halves
            XPa[g] = t4;
        }
    }
    float ux0 = xb[3], ux1 = xb[4], ux2 = xb[5];  // U = x(1)
    float vx0 = 0.f, vx1 = 0.f, vx2 = 0.f;        // V

    auto step = [&](const f32x4 (&XPin)[4], f32x4 (&XPout)[4],
                    float hx0, float hx1, float hx2,   // held x(t+1)
                    float& l0r, float& l1r, float& l2r, // load dest x(t+2)
                    int t) {
        // ---- 24 MFMA, C-init carries x-preacts (8 independent depth-3 chains)
        f32x4 acc[8];
#pragma unroll
        for (int cc = 0; cc < 8; ++cc) acc[cc] = MFMA16(Ah[cc].v, Bh.v, XPin[cc >> 1], 0, 0, 0);
#pragma unroll
        for (int cc = 0; cc < 8; ++cc) acc[cc] = MFMA16(Al[cc].v, Bh.v, acc[cc], 0, 0, 0);
#pragma unroll
        for (int cc = 0; cc < 8; ++cc) acc[cc] = MFMA16(Ah[cc].v, Bl.v, acc[cc], 0, 0, 0);

        // ---- prefetch x(t+2) (consumed by next step's XP compute) ----
        const int tn = (t + 2 < kT) ? t + 2 : kT - 1;
        l0r = xb[tn * 3 + 0];
        l1r = xb[tn * 3 + 1];
        l2r = xb[tn * 3 + 2];

        // ---- XP(t+1) from held x(t+1): exact fp32, off the MFMA path ----
#pragma unroll
        for (int g = 0; g < 4; ++g) {
            f32x2 p = fma2(sp2(hx0), xw[g][0],
                      fma2(sp2(hx1), xw[g][1],
                      fma2(sp2(hx2), xw[g][2], xbias[g])));
            f32x4 t4 = {p.x, p.y, p.x, p.y};
            XPout[g] = t4;
        }

        // ---- P select: chunk by qt>>1, element pair by qt&1 ----
        f32x2 P[4];
#pragma unroll
        for (int g = 0; g < 4; ++g) {
            const float a0 = selC ? acc[2 * g + 1][0] : acc[2 * g][0];
            const float a1 = selC ? acc[2 * g + 1][1] : acc[2 * g][1];
            const float a2 = selC ? acc[2 * g + 1][2] : acc[2 * g][2];
            const float a3 = selC ? acc[2 * g + 1][3] : acc[2 * g][3];
            f32x2 pv = {selE ? a2 : a0, selE ? a3 : a1};
            P[g] = pv;
        }

        // ---- c/h update for my 2 units, f32x2 packed ----
        const f32x2 one = {1.f, 1.f};
        f32x2 Ei = {fast_exp2(P[0].x), fast_exp2(P[0].y)};
        f32x2 Ef = {fast_exp2(P[1].x), fast_exp2(P[1].y)};
        f32x2 Eg = {fast_exp2(P[2].x), fast_exp2(P[2].y)};
        f32x2 Eo = {fast_exp2(P[3].x), fast_exp2(P[3].y)};
        f32x2 fd  = one + Ef;
        f32x2 sf  = {fast_rcp(fd.x), fast_rcp(fd.y)};
        f32x2 dd  = (one + Ei) * (one + Eg);
        f32x2 dig = {fast_rcp(dd.x), fast_rcp(dd.y)};
        f32x2 ig  = (one - Eg) * dig;
        f32x2 c   = fma2(sf, cst, ig);
        cst = c;
        f32x2 ca  = c * sp2(-2.0f * kL2E);
        f32x2 Ec  = {fast_exp2(ca.x), fast_exp2(ca.y)};
        Ec.x = fminf(Ec.x, 1e30f);                    // only overflow risk
        Ec.y = fminf(Ec.y, 1e30f);
        f32x2 od  = (one + Eo) * (one + Ec);
        f32x2 doc = {fast_rcp(od.x), fast_rcp(od.y)};
        h2 = (one - Ec) * doc;

        // ---- hi/lo packing: truncate-high via v_perm, residual -> lo ----
        const unsigned hh = pack_hi16(h2.x, h2.y);
        const float l0 = h2.x - __uint_as_float(__float_as_uint(h2.x) & 0xFFFF0000u);
        const float l1 = h2.y - __uint_as_float(__float_as_uint(h2.y) & 0xFFFF0000u);
        const unsigned hl = pack_hi16(l0, l1);

        // ---- B assembly: quad-lane j' holds units 8q+2j',+1 = k-dword j' ----
        Bh.d[0] = qb<0x00>(hh);   // quad_perm [0,0,0,0]
        Bh.d[1] = qb<0x55>(hh);   // [1,1,1,1]
        Bh.d[2] = qb<0xAA>(hh);   // [2,2,2,2]
        Bh.d[3] = qb<0xFF>(hh);   // [3,3,3,3]
        Bl.d[0] = qb<0x00>(hl);
        Bl.d[1] = qb<0x55>(hl);
        Bl.d[2] = qb<0xAA>(hl);
        Bl.d[3] = qb<0xFF>(hl);
    };

    for (int t = 0; t < kT; t += 2) {
        step(XPa, XPb, ux0, ux1, ux2, vx0, vx1, vx2, t);
        step(XPb, XPa, vx0, vx1, vx2, ux0, ux1, ux2, t + 1);
    }

    // ---- epilogue: out[b][o] = sum_u h_u W_fc[o][u] + b_fc[o] ----
    float s0 = h2.x * W_fc[u0]      + h2.y * W_fc[u0 + 1];
    float s1 = h2.x * W_fc[32 + u0] + h2.y * W_fc[32 + u0 + 1];
    // combine replica quarters (xor1, xor2) and k-quads (xor16, xor32)
    s0 += __shfl_xor(s0, 1, 64);  s1 += __shfl_xor(s1, 1, 64);
    s0 += __shfl_xor(s0, 2, 64);  s1 += __shfl_xor(s1, 2, 64);
    s0 += __shfl_xor(s0, 16, 64); s1 += __shfl_xor(s1, 16, 64);
    s0 += __shfl_xor(s0, 32, 64); s1 += __shfl_xor(s1, 32, 64);
    if (lane < 16 && (lane & 3) == 0) {
        out[(size_t)b * 2 + 0] = s0 + b_fc[0];
        out[(size_t)b * 2 + 1] = s1 + b_fc[1];
    }
}

extern "C" void kernel_launch(void* const* d_in, const int* in_sizes, int n_in,
                              void* d_out, int out_size, void* d_ws, size_t ws_size,
                              hipStream_t stream) {
    const float* x    = (const float*)d_in[0];
    const float* W_ih = (const float*)d_in[1];
    const float* W_hh = (const float*)d_in[2];
    const float* b_ih = (const float*)d_in[3];
    const float* b_hh = (const float*)d_in[4];
    const float* W_fc = (const float*)d_in[5];
    const float* b_fc = (const float*)d_in[6];
    float* out = (float*)d_out;

    const int batch = in_sizes[0] / (kT * 3);   // 8192
    dim3 grid(batch / 4);                       // 2048 blocks, 1 wave each
    dim3 block(64);                             // -> 2 waves per SIMD
    hipLaunchKernelGGL(lstm_rep4, grid, block, 0, stream,
                       x, W_ih, W_hh, b_ih, b_hh, W_fc, b_fc, out);
}

// Round 3
// 466.152 us; speedup vs baseline: 1.0712x; 1.0712x over previous
//
#include <hip/hip_runtime.h>
#include <math.h>

// LSTM B=8192,T=512,IN=3,H=32,OUT=2 fp32.
// R11 = R10 with the s_getreg fixed (builtin + numeric hwreg encoding; the
// gfx950 assembler rejects symbolic hwreg(HW_ID,...) in inline asm).
// R9 post-mortem: wall = VALU-time + MFMA-time exactly (phase-locked waves:
// both co-resident waves issue MFMA bursts simultaneously -> matrix-port
// contention, then VALU bursts simultaneously -> no cross-pipe overlap).
// Fix: co-resident waves occupy DISTINCT hw wave slots (HW_ID bits [3:0] =
// WAVE_ID on gfx9-lineage); odd-slot waves s_sleep ~320 cyc once before the
// t-loop. With no barriers and identical per-step work, the offset persists
// all 512 steps -> one wave's 24-MFMA burst hides under the partner's
// gate-math VALU burst.
// Everything else identical to R9 (verified correct, absmax 4.88e-4):
// 4 batches/wave, 4-fold column replication, 2048 waves = 2/SIMD,
// B rebuild via 8 quad_perm DPP broadcasts, x-preacts ride MFMA C operand,
// f32x2 gate math, 24 MFMA + 16 trans per step per wave.

namespace {
constexpr int   kT   = 512;
constexpr float kL2E = 1.44269504088896340736f;
}

typedef __bf16 bf16x8 __attribute__((ext_vector_type(8)));
typedef float  f32x4  __attribute__((ext_vector_type(4)));
typedef float  f32x2  __attribute__((ext_vector_type(2)));

union Frag {
    bf16x8 v;
    unsigned short u[8];
    unsigned int   d[4];
};

__device__ __forceinline__ unsigned short bf_rne(float f) {
    unsigned u = __float_as_uint(f);
    u += 0x7fffu + ((u >> 16) & 1u);
    return (unsigned short)(u >> 16);
}
__device__ __forceinline__ float bf_tof(unsigned short h) {
    return __uint_as_float((unsigned)h << 16);
}
__device__ __forceinline__ float fast_exp2(float v) { return __builtin_amdgcn_exp2f(v); }
__device__ __forceinline__ float fast_rcp(float v)  { return __builtin_amdgcn_rcpf(v); }

// pack the high-16 bits (bf16 truncation) of two fp32 into one dword:
// result = [lo16 = a.hi16, hi16 = b.hi16]
__device__ __forceinline__ unsigned pack_hi16(float a, float b) {
    return __builtin_amdgcn_perm(__float_as_uint(b), __float_as_uint(a), 0x07060302u);
}

// DPP quad_perm broadcast of quad-lane J to all 4 lanes of the quad.
template <int CTRL>
__device__ __forceinline__ unsigned qb(unsigned v) {
    return (unsigned)__builtin_amdgcn_mov_dpp((int)v, CTRL, 0xF, 0xF, true);
}

__device__ __forceinline__ f32x2 fma2(f32x2 a, f32x2 b, f32x2 c) {
    return __builtin_elementwise_fma(a, b, c);
}
__device__ __forceinline__ f32x2 sp2(float v) {
    f32x2 r = {v, v};
    return r;
}

#define MFMA16 __builtin_amdgcn_mfma_f32_16x16x32_bf16

extern "C" __global__ __launch_bounds__(64, 2)
void lstm_rep4s(const float* __restrict__ x,
                const float* __restrict__ W_ih,
                const float* __restrict__ W_hh,
                const float* __restrict__ b_ih,
                const float* __restrict__ b_hh,
                const float* __restrict__ W_fc,
                const float* __restrict__ b_fc,
                float* __restrict__ out) {
    const int  lane = threadIdx.x & 63;
    const int  n    = lane & 15;        // B/D column == A row
    const int  q    = lane >> 4;        // quad-of-k / row group
    const int  qt   = n & 3;            // replica quarter (lane position in quad)
    const int  bat  = n >> 2;           // batch within wave (0..3)
    const int  b    = blockIdx.x * 4 + bat;
    const bool selC = (qt & 2) != 0;    // chunk (pc) select
    const bool selE = (qt & 1) != 0;    // element-pair select

    // ---- A-frags: permuted scaled W_hh (hi/lo) ----
    // chunk cc (g=cc>>1, pc=cc&1): A row m holds W row
    // R = 32g + 8(m>>2) + 4pc + (m&3)  =>  D row 4q+r of chunk cc is
    // gate g, unit u = 8q + 4pc + r (verified R3/R5; unchanged by col pairing).
    Frag Ah[8], Al[8];
#pragma unroll
    for (int cc = 0; cc < 8; ++cc) {
        const int   g  = cc >> 1, pc = cc & 1;
        const float s  = (g == 2) ? -2.0f * kL2E : -kL2E;
        const int   R  = 32 * g + 8 * (n >> 2) + 4 * pc + (n & 3);
#pragma unroll
        for (int j = 0; j < 8; ++j) {
            const float w = W_hh[R * 32 + 8 * q + j] * s;
            const unsigned short hb = bf_rne(w);
            Ah[cc].u[j] = hb;
            Al[cc].u[j] = bf_rne(w - bf_tof(hb));
        }
    }

    // ---- per-lane x-path constants for my 2 units (u0, u0+1) x 4 gates ----
    const int u0 = 8 * q + 2 * qt;
    f32x2 xw[4][3], xbias[4];
#pragma unroll
    for (int g = 0; g < 4; ++g) {
        const float s  = (g == 2) ? -2.0f * kL2E : -kL2E;
        const int   R0 = 32 * g + u0, R1 = R0 + 1;
#pragma unroll
        for (int k = 0; k < 3; ++k) {
            f32x2 w = {W_ih[R0 * 3 + k] * s, W_ih[R1 * 3 + k] * s};
            xw[g][k] = w;
        }
        f32x2 bb = {(b_ih[R0] + b_hh[R0]) * s, (b_ih[R1] + b_hh[R1]) * s};
        xbias[g] = bb;
    }

    const float* xb = x + (size_t)b * kT * 3;

    f32x2 cst = {0.f, 0.f};
    f32x2 h2  = {0.f, 0.f};
    Frag Bh, Bl;
#pragma unroll
    for (int j = 0; j < 4; ++j) { Bh.d[j] = 0; Bl.d[j] = 0; }

    // ---- pipeline prologue: XPa = XP(0) from x[0]; U = x(1) ----
    f32x4 XPa[4], XPb[4];
    {
        const float a0 = xb[0], a1 = xb[1], a2 = xb[2];
#pragma unroll
        for (int g = 0; g < 4; ++g) {
            f32x2 p = fma2(sp2(a0), xw[g][0],
                      fma2(sp2(a1), xw[g][1],
                      fma2(sp2(a2), xw[g][2], xbias[g])));
            f32x4 t4 = {p.x, p.y, p.x, p.y};  // correct for both selE halves
            XPa[g] = t4;
        }
    }
    float ux0 = xb[3], ux1 = xb[4], ux2 = xb[5];  // U = x(1)
    float vx0 = 0.f, vx1 = 0.f, vx2 = 0.f;        // V

    // ---- anti-phase stagger (the R10/R11 change) ----
    // Co-resident waves on a SIMD hold distinct wave slots. Odd-slot waves
    // delay ~320 cyc (~half step) once; the offset persists (no barriers,
    // identical per-step work) -> MFMA burst of one wave overlaps the
    // partner's VALU burst instead of phase-locking with its MFMA burst.
    // s_getreg imm encoding: (size-1)<<11 | offset<<6 | id; HW_ID = id 4,
    // WAVE_ID = bits [3:0] (gfx9 lineage).
    {
        const unsigned hwid = __builtin_amdgcn_s_getreg((3 << 11) | (0 << 6) | 4);
        if (hwid & 1u) {
            __builtin_amdgcn_s_sleep(5);   // ~320 cycles
        }
    }

    auto step = [&](const f32x4 (&XPin)[4], f32x4 (&XPout)[4],
                    float hx0, float hx1, float hx2,   // held x(t+1)
                    float& l0r, float& l1r, float& l2r, // load dest x(t+2)
                    int t) {
        // ---- 24 MFMA, C-init carries x-preacts (8 independent depth-3 chains)
        f32x4 acc[8];
#pragma unroll
        for (int cc = 0; cc < 8; ++cc) acc[cc] = MFMA16(Ah[cc].v, Bh.v, XPin[cc >> 1], 0, 0, 0);
#pragma unroll
        for (int cc = 0; cc < 8; ++cc) acc[cc] = MFMA16(Al[cc].v, Bh.v, acc[cc], 0, 0, 0);
#pragma unroll
        for (int cc = 0; cc < 8; ++cc) acc[cc] = MFMA16(Ah[cc].v, Bl.v, acc[cc], 0, 0, 0);

        // ---- prefetch x(t+2) (consumed by next step's XP compute) ----
        const int tn = (t + 2 < kT) ? t + 2 : kT - 1;
        l0r = xb[tn * 3 + 0];
        l1r = xb[tn * 3 + 1];
        l2r = xb[tn * 3 + 2];

        // ---- XP(t+1) from held x(t+1): exact fp32, off the MFMA path ----
#pragma unroll
        for (int g = 0; g < 4; ++g) {
            f32x2 p = fma2(sp2(hx0), xw[g][0],
                      fma2(sp2(hx1), xw[g][1],
                      fma2(sp2(hx2), xw[g][2], xbias[g])));
            f32x4 t4 = {p.x, p.y, p.x, p.y};
            XPout[g] = t4;
        }

        // ---- P select: chunk by qt>>1, element pair by qt&1 ----
        f32x2 P[4];
#pragma unroll
        for (int g = 0; g < 4; ++g) {
            const float a0 = selC ? acc[2 * g + 1][0] : acc[2 * g][0];
            const float a1 = selC ? acc[2 * g + 1][1] : acc[2 * g][1];
            const float a2 = selC ? acc[2 * g + 1][2] : acc[2 * g][2];
            const float a3 = selC ? acc[2 * g + 1][3] : acc[2 * g][3];
            f32x2 pv = {selE ? a2 : a0, selE ? a3 : a1};
            P[g] = pv;
        }

        // ---- c/h update for my 2 units, f32x2 packed ----
        const f32x2 one = {1.f, 1.f};
        f32x2 Ei = {fast_exp2(P[0].x), fast_exp2(P[0].y)};
        f32x2 Ef = {fast_exp2(P[1].x), fast_exp2(P[1].y)};
        f32x2 Eg = {fast_exp2(P[2].x), fast_exp2(P[2].y)};
        f32x2 Eo = {fast_exp2(P[3].x), fast_exp2(P[3].y)};
        f32x2 fd  = one + Ef;
        f32x2 sf  = {fast_rcp(fd.x), fast_rcp(fd.y)};
        f32x2 dd  = (one + Ei) * (one + Eg);
        f32x2 dig = {fast_rcp(dd.x), fast_rcp(dd.y)};
        f32x2 ig  = (one - Eg) * dig;
        f32x2 c   = fma2(sf, cst, ig);
        cst = c;
        f32x2 ca  = c * sp2(-2.0f * kL2E);
        f32x2 Ec  = {fast_exp2(ca.x), fast_exp2(ca.y)};
        Ec.x = fminf(Ec.x, 1e30f);                    // only overflow risk
        Ec.y = fminf(Ec.y, 1e30f);
        f32x2 od  = (one + Eo) * (one + Ec);
        f32x2 doc = {fast_rcp(od.x), fast_rcp(od.y)};
        h2 = (one - Ec) * doc;

        // ---- hi/lo packing: truncate-high via v_perm, residual -> lo ----
        const unsigned hh = pack_hi16(h2.x, h2.y);
        const float l0 = h2.x - __uint_as_float(__float_as_uint(h2.x) & 0xFFFF0000u);
        const float l1 = h2.y - __uint_as_float(__float_as_uint(h2.y) & 0xFFFF0000u);
        const unsigned hl = pack_hi16(l0, l1);

        // ---- B assembly: quad-lane j' holds units 8q+2j',+1 = k-dword j' ----
        Bh.d[0] = qb<0x00>(hh);   // quad_perm [0,0,0,0]
        Bh.d[1] = qb<0x55>(hh);   // [1,1,1,1]
        Bh.d[2] = qb<0xAA>(hh);   // [2,2,2,2]
        Bh.d[3] = qb<0xFF>(hh);   // [3,3,3,3]
        Bl.d[0] = qb<0x00>(hl);
        Bl.d[1] = qb<0x55>(hl);
        Bl.d[2] = qb<0xAA>(hl);
        Bl.d[3] = qb<0xFF>(hl);
    };

    for (int t = 0; t < kT; t += 2) {
        step(XPa, XPb, ux0, ux1, ux2, vx0, vx1, vx2, t);
        step(XPb, XPa, vx0, vx1, vx2, ux0, ux1, ux2, t + 1);
    }

    // ---- epilogue: out[b][o] = sum_u h_u W_fc[o][u] + b_fc[o] ----
    float s0 = h2.x * W_fc[u0]      + h2.y * W_fc[u0 + 1];
    float s1 = h2.x * W_fc[32 + u0] + h2.y * W_fc[32 + u0 + 1];
    // combine replica quarters (xor1, xor2) and k-quads (xor16, xor32)
    s0 += __shfl_xor(s0, 1, 64);  s1 += __shfl_xor(s1, 1, 64);
    s0 += __shfl_xor(s0, 2, 64);  s1 += __shfl_xor(s1, 2, 64);
    s0 += __shfl_xor(s0, 16, 64); s1 += __shfl_xor(s1, 16, 64);
    s0 += __shfl_xor(s0, 32, 64); s1 += __shfl_xor(s1, 32, 64);
    if (lane < 16 && (lane & 3) == 0) {
        out[(size_t)b * 2 + 0] = s0 + b_fc[0];
        out[(size_t)b * 2 + 1] = s1 + b_fc[1];
    }
}

extern "C" void kernel_launch(void* const* d_in, const int* in_sizes, int n_in,
                              void* d_out, int out_size, void* d_ws, size_t ws_size,
                              hipStream_t stream) {
    const float* x    = (const float*)d_in[0];
    const float* W_ih = (const float*)d_in[1];
    const float* W_hh = (const float*)d_in[2];
    const float* b_ih = (const float*)d_in[3];
    const float* b_hh = (const float*)d_in[4];
    const float* W_fc = (const float*)d_in[5];
    const float* b_fc = (const float*)d_in[6];
    float* out = (float*)d_out;

    const int batch = in_sizes[0] / (kT * 3);   // 8192
    dim3 grid(batch / 4);                       // 2048 blocks, 1 wave each
    dim3 block(64);                             // -> 2 waves per SIMD
    hipLaunchKernelGGL(lstm_rep4s, grid, block, 0, stream,
                       x, W_ih, W_hh, b_ih, b_hh, W_fc, b_fc, out);
}

// Round 4
// 315.388 us; speedup vs baseline: 1.5833x; 1.4780x over previous
//
#include <hip/hip_runtime.h>
#include <math.h>

// LSTM B=8192,T=512,IN=3,H=32,OUT=2 fp32.
// R12: 4-wave unit-split, zero replication.
// R11 post-mortem: SIMD fully saturated, wall = VALU-cyc + MFMA-cyc (additive
// on one SIMD). Only fix: reduce cycles. Replication is the MFMA-work
// multiplier (R8 2x, R11 4x) -> eliminate it.
// Structure: block = 256 thr (4 waves) on 16 DISTINCT batches; wave w owns
// units 8w..8w+7. Per wave: A = 2 chunks x 16 rows (8 units x 4 gates),
// permuted A row m -> W row 32*(m&3) + 8w + 4c + (m>>2), so lane(n,q)
// acc_c[r] = gate r of unit 8w+4c+q, batch n: NO selects, NO cross-lane.
// 6 MFMA/step/wave (2 indep depth-3 hi/lo chains) for 16 batches =
// 1/4 the MFMA work of R11. h hi/lo exchanged via double-buffered LDS
// [batch][unit] (stride 40 ushort: 16B-aligned, conflict-minimal
// ds_read_b128), 1 barrier/step. grid 512 x 256 -> 2 blocks/CU ->
// 2 waves/SIMD: partner block hides barrier/LDS latency.
// Gate math: fused triple-rcp c-update (7 trans/unit vs 8):
// c = [cst*(1+Ei)(1+Eg) + (1-Eg)(1+Ef)] / [(1+Ef)(1+Ei)(1+Eg)].
// x-preacts exact fp32 in MFMA C operand (all 16 C slots used).

namespace {
constexpr int   kT      = 512;
constexpr float kL2E    = 1.44269504088896340736f;
constexpr int   kStride = 40;   // ushorts per LDS row: 32 units + 8 pad
}

typedef __bf16 bf16x8 __attribute__((ext_vector_type(8)));
typedef float  f32x4  __attribute__((ext_vector_type(4)));
typedef float  f32x2  __attribute__((ext_vector_type(2)));
typedef unsigned int u32x4 __attribute__((ext_vector_type(4)));

union Frag {
    bf16x8 v;
    unsigned short u[8];
    unsigned int   d[4];
    u32x4          q4;
};

__device__ __forceinline__ unsigned short bf_rne(float f) {
    unsigned u = __float_as_uint(f);
    u += 0x7fffu + ((u >> 16) & 1u);
    return (unsigned short)(u >> 16);
}
__device__ __forceinline__ float bf_tof(unsigned short h) {
    return __uint_as_float((unsigned)h << 16);
}
__device__ __forceinline__ float fast_exp2(float v) { return __builtin_amdgcn_exp2f(v); }
__device__ __forceinline__ float fast_rcp(float v)  { return __builtin_amdgcn_rcpf(v); }

__device__ __forceinline__ f32x2 fma2(f32x2 a, f32x2 b, f32x2 c) {
    return __builtin_elementwise_fma(a, b, c);
}
__device__ __forceinline__ f32x2 exp22(f32x2 v) {
    f32x2 r = {fast_exp2(v.x), fast_exp2(v.y)};
    return r;
}
__device__ __forceinline__ f32x2 rcp2(f32x2 v) {
    f32x2 r = {fast_rcp(v.x), fast_rcp(v.y)};
    return r;
}

#define MFMA16 __builtin_amdgcn_mfma_f32_16x16x32_bf16

extern "C" __global__ __launch_bounds__(256, 2)
void lstm_split(const float* __restrict__ x,
                const float* __restrict__ W_ih,
                const float* __restrict__ W_hh,
                const float* __restrict__ b_ih,
                const float* __restrict__ b_hh,
                const float* __restrict__ W_fc,
                const float* __restrict__ b_fc,
                float* __restrict__ out) {
    const int tid  = threadIdx.x;
    const int lane = tid & 63;
    const int w    = tid >> 6;          // wave id 0..3: owns units 8w..8w+7
    const int n    = lane & 15;         // batch-within-block == B/D column
    const int q    = lane >> 4;         // k-quad / D row group
    const int blk  = blockIdx.x;
    const int batch = blk * 16 + n;

    // double-buffered h planes: [buf][hi/lo][batch][unit+pad]
    __shared__ __align__(16) unsigned short lds_h[2][2][16][kStride];

    // ---- A frags: chunk c covers units 8w+4c..+3, rows permuted so that
    // A row m holds W row R(m) = 32*(m&3) + 8w + 4c + (m>>2).
    // (HW layout, verified in prior rounds: A row = lane&15, k = 8q+j;
    //  D col = lane&15, row = 4q+reg.)  => acc_c[r] = gate r, unit 8w+4c+q.
    Frag Ah[2], Al[2];
#pragma unroll
    for (int c = 0; c < 2; ++c) {
        const int   g = n & 3;
        const float s = (g == 2) ? -2.0f * kL2E : -kL2E;
        const int   R = 32 * g + 8 * w + 4 * c + (n >> 2);
#pragma unroll
        for (int j = 0; j < 8; ++j) {
            const float wv = W_hh[R * 32 + 8 * q + j] * s;
            const unsigned short hb = bf_rne(wv);
            Ah[c].u[j] = hb;
            Al[c].u[j] = bf_rne(wv - bf_tof(hb));
        }
    }

    // ---- x-path constants: my 2 units (8w+q, 8w+4+q) x 4 gates ----
    float xw[2][4][3], xbias[2][4];
#pragma unroll
    for (int c = 0; c < 2; ++c)
#pragma unroll
        for (int g = 0; g < 4; ++g) {
            const float s = (g == 2) ? -2.0f * kL2E : -kL2E;
            const int   R = 32 * g + 8 * w + 4 * c + q;
#pragma unroll
            for (int k = 0; k < 3; ++k) xw[c][g][k] = W_ih[R * 3 + k] * s;
            xbias[c][g] = (b_ih[R] + b_hh[R]) * s;
        }

    const float* xb = x + (size_t)batch * kT * 3;

    f32x2 cst = {0.f, 0.f};
    Frag Bh, Bl;
#pragma unroll
    for (int j = 0; j < 4; ++j) { Bh.d[j] = 0; Bl.d[j] = 0; }

    // prologue: xpC = XP(0); xc = x(1)
    f32x4 xpC[2];
    {
        const float a0 = xb[0], a1 = xb[1], a2 = xb[2];
#pragma unroll
        for (int c = 0; c < 2; ++c)
#pragma unroll
            for (int r = 0; r < 4; ++r)
                xpC[c][r] = fmaf(a0, xw[c][r][0],
                            fmaf(a1, xw[c][r][1],
                            fmaf(a2, xw[c][r][2], xbias[c][r])));
    }
    float xc0 = xb[3], xc1 = xb[4], xc2 = xb[5];

    const int u0 = 8 * w + q;           // chunk-0 unit
    const int u1 = 8 * w + 4 + q;       // chunk-1 unit

    for (int t = 0; t < kT; ++t) {
        // ---- 6 MFMA: 2 independent depth-3 hi/lo chains, C carries xp ----
        f32x4 a0 = MFMA16(Ah[0].v, Bh.v, xpC[0], 0, 0, 0);
        f32x4 a1 = MFMA16(Ah[1].v, Bh.v, xpC[1], 0, 0, 0);
        a0 = MFMA16(Al[0].v, Bh.v, a0, 0, 0, 0);
        a1 = MFMA16(Al[1].v, Bh.v, a1, 0, 0, 0);
        a0 = MFMA16(Ah[0].v, Bl.v, a0, 0, 0, 0);
        a1 = MFMA16(Ah[1].v, Bl.v, a1, 0, 0, 0);

        // ---- shadow work: prefetch x(t+2), XP(t+1) from held x(t+1) ----
        const int tn = (t + 2 < kT) ? t + 2 : kT - 1;
        const float xn0 = xb[tn * 3 + 0];
        const float xn1 = xb[tn * 3 + 1];
        const float xn2 = xb[tn * 3 + 2];
#pragma unroll
        for (int c = 0; c < 2; ++c)
#pragma unroll
            for (int r = 0; r < 4; ++r)
                xpC[c][r] = fmaf(xc0, xw[c][r][0],
                            fmaf(xc1, xw[c][r][1],
                            fmaf(xc2, xw[c][r][2], xbias[c][r])));

        // ---- gate math, f32x2 over (unit u0, unit u1): acc_c[r] = gate r ----
        const f32x2 one = {1.f, 1.f};
        f32x2 P0 = {a0[0], a1[0]};
        f32x2 P1 = {a0[1], a1[1]};
        f32x2 P2 = {a0[2], a1[2]};
        f32x2 P3 = {a0[3], a1[3]};
        f32x2 Ei = exp22(P0);
        f32x2 Ef = exp22(P1);
        f32x2 Eg = exp22(P2);
        f32x2 Eo = exp22(P3);
        f32x2 pf  = one + Ef;
        f32x2 pi  = one + Ei;
        f32x2 pg  = one + Eg;
        f32x2 tig = pi * pg;
        f32x2 den = tig * pf;
        f32x2 num = fma2(cst, tig, (one - Eg) * pf);
        f32x2 c   = num * rcp2(den);
        cst = c;
        f32x2 ca  = c * (f32x2){-2.0f * kL2E, -2.0f * kL2E};
        f32x2 Ec  = exp22(ca);
        Ec.x = fminf(Ec.x, 1e30f);
        Ec.y = fminf(Ec.y, 1e30f);
        f32x2 od  = (one + Eo) * (one + Ec);
        f32x2 h2  = (one - Ec) * rcp2(od);

        // ---- pack hi/lo (truncate-high + residual) and exchange via LDS ----
        const unsigned bx = __float_as_uint(h2.x);
        const unsigned by = __float_as_uint(h2.y);
        const unsigned short hi0 = (unsigned short)(bx >> 16);
        const unsigned short hi1 = (unsigned short)(by >> 16);
        const float lo0f = h2.x - __uint_as_float(bx & 0xFFFF0000u);
        const float lo1f = h2.y - __uint_as_float(by & 0xFFFF0000u);
        const unsigned short lo0 = (unsigned short)(__float_as_uint(lo0f) >> 16);
        const unsigned short lo1 = (unsigned short)(__float_as_uint(lo1f) >> 16);

        const int buf = t & 1;
        lds_h[buf][0][n][u0] = hi0;
        lds_h[buf][0][n][u1] = hi1;
        lds_h[buf][1][n][u0] = lo0;
        lds_h[buf][1][n][u1] = lo1;

        __syncthreads();

        // ---- B frags for next step: units 8q..8q+7 of batch n ----
        Bh.q4 = *(const u32x4*)&lds_h[buf][0][n][8 * q];
        Bl.q4 = *(const u32x4*)&lds_h[buf][1][n][8 * q];

        xc0 = xn0; xc1 = xn1; xc2 = xn2;
    }

    // ---- epilogue (wave 0): h(511) is in lds buf 1 ----
    if (w == 0) {
        Frag Hh, Hl;
        Hh.q4 = *(const u32x4*)&lds_h[1][0][n][8 * q];
        Hl.q4 = *(const u32x4*)&lds_h[1][1][n][8 * q];
        float s0 = 0.f, s1 = 0.f;
#pragma unroll
        for (int j = 0; j < 8; ++j) {
            const float hv = bf_tof(Hh.u[j]) + bf_tof(Hl.u[j]);
            const int   u  = 8 * q + j;
            s0 = fmaf(hv, W_fc[u], s0);
            s1 = fmaf(hv, W_fc[32 + u], s1);
        }
        s0 += __shfl_xor(s0, 16, 64); s1 += __shfl_xor(s1, 16, 64);
        s0 += __shfl_xor(s0, 32, 64); s1 += __shfl_xor(s1, 32, 64);
        if (lane < 16) {
            out[(size_t)batch * 2 + 0] = s0 + b_fc[0];
            out[(size_t)batch * 2 + 1] = s1 + b_fc[1];
        }
    }
}

extern "C" void kernel_launch(void* const* d_in, const int* in_sizes, int n_in,
                              void* d_out, int out_size, void* d_ws, size_t ws_size,
                              hipStream_t stream) {
    const float* x    = (const float*)d_in[0];
    const float* W_ih = (const float*)d_in[1];
    const float* W_hh = (const float*)d_in[2];
    const float* b_ih = (const float*)d_in[3];
    const float* b_hh = (const float*)d_in[4];
    const float* W_fc = (const float*)d_in[5];
    const float* b_fc = (const float*)d_in[6];
    float* out = (float*)d_out;

    const int batch = in_sizes[0] / (kT * 3);   // 8192
    dim3 grid(batch / 16);                      // 512 blocks of 4 waves
    dim3 block(256);                            // -> 2 blocks/CU, 2 waves/SIMD
    hipLaunchKernelGGL(lstm_split, grid, block, 0, stream,
                       x, W_ih, W_hh, b_ih, b_hh, W_fc, b_fc, out);
}

// Round 5
// 311.461 us; speedup vs baseline: 1.6032x; 1.0126x over previous
//
#include <hip/hip_runtime.h>
#include <math.h>

// LSTM B=8192,T=512,IN=3,H=32,OUT=2 fp32.
// R13 = R12 (4-wave unit-split, LDS h-exchange) + three riders:
// 1) Block anti-phase stagger: per SIMD the 2 co-resident waves are from 2
//    different blocks doing identical per-step work -> phase-lock (R12 idle
//    33%). One-time s_sleep(8) on (bid^(bid>>8))&1 (bit differs within the
//    co-resident pair under both round-robin and consecutive dispatch).
// 2) Adjacent-unit A-permutation: R(m) = 32*(m&3) + 8w + 2*(m>>2) + c ->
//    lane's 2 units are u0=8w+2q, u0+1. h hi/lo packed per-plane with ONE
//    v_cvt_pk_bf16_f32 and stored as ONE ds_write_b32 (was 4 u16 writes),
//    uniform 2-way write banks (free). RNE hi + exact residual lo.
// 3) XP via 12 v_pk_fma_f32 over (u0,u1) pairs (was 24 scalar FMA).
// Unchanged: 6 MFMA/step/wave (2 indep hi/lo depth-3 chains, C carries xp),
// fused triple-rcp c-update, double-buffered LDS [buf][plane][batch][40],
// 1 barrier/step, grid 512x256 = 2 blocks/CU = 2 waves/SIMD.

namespace {
constexpr int   kT      = 512;
constexpr float kL2E    = 1.44269504088896340736f;
constexpr int   kStride = 40;   // ushorts per LDS row: 32 units + 8 pad
}

typedef __bf16 bf16x8 __attribute__((ext_vector_type(8)));
typedef float  f32x4  __attribute__((ext_vector_type(4)));
typedef float  f32x2  __attribute__((ext_vector_type(2)));
typedef unsigned int u32x4 __attribute__((ext_vector_type(4)));

union Frag {
    bf16x8 v;
    unsigned short u[8];
    unsigned int   d[4];
    u32x4          q4;
};

__device__ __forceinline__ unsigned short bf_rne(float f) {
    unsigned u = __float_as_uint(f);
    u += 0x7fffu + ((u >> 16) & 1u);
    return (unsigned short)(u >> 16);
}
__device__ __forceinline__ float bf_tof(unsigned short h) {
    return __uint_as_float((unsigned)h << 16);
}
__device__ __forceinline__ float fast_exp2(float v) { return __builtin_amdgcn_exp2f(v); }
__device__ __forceinline__ float fast_rcp(float v)  { return __builtin_amdgcn_rcpf(v); }

// v_cvt_pk_bf16_f32: dst = [lo16 = bf16_rne(a), hi16 = bf16_rne(b)]
__device__ __forceinline__ unsigned cvt_pk_bf16(float a, float b) {
    unsigned r;
    asm("v_cvt_pk_bf16_f32 %0, %1, %2" : "=v"(r) : "v"(a), "v"(b));
    return r;
}

__device__ __forceinline__ f32x2 fma2(f32x2 a, f32x2 b, f32x2 c) {
    return __builtin_elementwise_fma(a, b, c);
}
__device__ __forceinline__ f32x2 exp22(f32x2 v) {
    f32x2 r = {fast_exp2(v.x), fast_exp2(v.y)};
    return r;
}
__device__ __forceinline__ f32x2 rcp2(f32x2 v) {
    f32x2 r = {fast_rcp(v.x), fast_rcp(v.y)};
    return r;
}
__device__ __forceinline__ f32x2 sp2(float v) {
    f32x2 r = {v, v};
    return r;
}

#define MFMA16 __builtin_amdgcn_mfma_f32_16x16x32_bf16

extern "C" __global__ __launch_bounds__(256, 2)
void lstm_split2(const float* __restrict__ x,
                 const float* __restrict__ W_ih,
                 const float* __restrict__ W_hh,
                 const float* __restrict__ b_ih,
                 const float* __restrict__ b_hh,
                 const float* __restrict__ W_fc,
                 const float* __restrict__ b_fc,
                 float* __restrict__ out) {
    const int tid  = threadIdx.x;
    const int lane = tid & 63;
    const int w    = tid >> 6;          // wave id 0..3
    const int n    = lane & 15;         // batch-within-block == B/D column
    const int q    = lane >> 4;         // k-quad / D row group
    const int bid  = blockIdx.x;
    const int batch = bid * 16 + n;

    // double-buffered h planes: [buf][hi/lo][batch][unit+pad]
    __shared__ __align__(16) unsigned short lds_h[2][2][16][kStride];

    // ---- A frags: chunk c, A row m -> W row R(m) = 32*(m&3)+8w+2*(m>>2)+c.
    // HW: A row = lane&15 (=n), k = 8q+j; D col = lane&15, row = 4q+reg.
    // => acc_c[r] = gate r of unit u = 8w + 2q + c (ADJACENT units per lane).
    Frag Ah[2], Al[2];
#pragma unroll
    for (int c = 0; c < 2; ++c) {
        const int   g = n & 3;
        const float s = (g == 2) ? -2.0f * kL2E : -kL2E;
        const int   R = 32 * g + 8 * w + 2 * (n >> 2) + c;
#pragma unroll
        for (int j = 0; j < 8; ++j) {
            const float wv = W_hh[R * 32 + 8 * q + j] * s;
            const unsigned short hb = bf_rne(wv);
            Ah[c].u[j] = hb;
            Al[c].u[j] = bf_rne(wv - bf_tof(hb));
        }
    }

    // ---- x-path constants: units (u0, u0+1) x 4 gates, f32x2-paired ----
    const int u0 = 8 * w + 2 * q;
    f32x2 xwp[4][3], xbp[4];
#pragma unroll
    for (int g = 0; g < 4; ++g) {
        const float s  = (g == 2) ? -2.0f * kL2E : -kL2E;
        const int   R0 = 32 * g + u0, R1 = R0 + 1;
#pragma unroll
        for (int k = 0; k < 3; ++k) {
            f32x2 wv = {W_ih[R0 * 3 + k] * s, W_ih[R1 * 3 + k] * s};
            xwp[g][k] = wv;
        }
        f32x2 bb = {(b_ih[R0] + b_hh[R0]) * s, (b_ih[R1] + b_hh[R1]) * s};
        xbp[g] = bb;
    }

    const float* xb = x + (size_t)batch * kT * 3;

    f32x2 cst = {0.f, 0.f};
    Frag Bh, Bl;
#pragma unroll
    for (int j = 0; j < 4; ++j) { Bh.d[j] = 0; Bl.d[j] = 0; }

    // prologue: xpC = XP(0); xc = x(1)
    f32x4 xpC0, xpC1;
    {
        const float a0 = xb[0], a1 = xb[1], a2 = xb[2];
#pragma unroll
        for (int g = 0; g < 4; ++g) {
            f32x2 p = fma2(sp2(a0), xwp[g][0],
                      fma2(sp2(a1), xwp[g][1],
                      fma2(sp2(a2), xwp[g][2], xbp[g])));
            xpC0[g] = p.x;
            xpC1[g] = p.y;
        }
    }
    float xc0 = xb[3], xc1 = xb[4], xc2 = xb[5];

    // ---- block anti-phase stagger (one-time, ~512 cyc ~ half step) ----
    if ((bid ^ (bid >> 8)) & 1) {
        __builtin_amdgcn_s_sleep(8);
    }

    for (int t = 0; t < kT; ++t) {
        // ---- 6 MFMA: 2 independent depth-3 hi/lo chains, C carries xp ----
        f32x4 a0 = MFMA16(Ah[0].v, Bh.v, xpC0, 0, 0, 0);
        f32x4 a1 = MFMA16(Ah[1].v, Bh.v, xpC1, 0, 0, 0);
        a0 = MFMA16(Al[0].v, Bh.v, a0, 0, 0, 0);
        a1 = MFMA16(Al[1].v, Bh.v, a1, 0, 0, 0);
        a0 = MFMA16(Ah[0].v, Bl.v, a0, 0, 0, 0);
        a1 = MFMA16(Ah[1].v, Bl.v, a1, 0, 0, 0);

        // ---- shadow work: prefetch x(t+2), XP(t+1) from held x(t+1) ----
        const int tn = (t + 2 < kT) ? t + 2 : kT - 1;
        const float xn0 = xb[tn * 3 + 0];
        const float xn1 = xb[tn * 3 + 1];
        const float xn2 = xb[tn * 3 + 2];
#pragma unroll
        for (int g = 0; g < 4; ++g) {
            f32x2 p = fma2(sp2(xc0), xwp[g][0],
                      fma2(sp2(xc1), xwp[g][1],
                      fma2(sp2(xc2), xwp[g][2], xbp[g])));
            xpC0[g] = p.x;
            xpC1[g] = p.y;
        }

        // ---- gate math, f32x2 over (u0, u0+1): acc_c[r] = gate r ----
        const f32x2 one = {1.f, 1.f};
        f32x2 P0 = {a0[0], a1[0]};
        f32x2 P1 = {a0[1], a1[1]};
        f32x2 P2 = {a0[2], a1[2]};
        f32x2 P3 = {a0[3], a1[3]};
        f32x2 Ei = exp22(P0);
        f32x2 Ef = exp22(P1);
        f32x2 Eg = exp22(P2);
        f32x2 Eo = exp22(P3);
        f32x2 pf  = one + Ef;
        f32x2 pi  = one + Ei;
        f32x2 pg  = one + Eg;
        f32x2 tig = pi * pg;
        f32x2 den = tig * pf;
        f32x2 num = fma2(cst, tig, (one - Eg) * pf);
        f32x2 c   = num * rcp2(den);
        cst = c;
        f32x2 ca  = c * sp2(-2.0f * kL2E);
        f32x2 Ec  = exp22(ca);
        Ec.x = fminf(Ec.x, 1e30f);
        Ec.y = fminf(Ec.y, 1e30f);
        f32x2 od  = (one + Eo) * (one + Ec);
        f32x2 h2  = (one - Ec) * rcp2(od);

        // ---- pack: RNE hi via cvt_pk, exact residual lo via cvt_pk ----
        const unsigned hh  = cvt_pk_bf16(h2.x, h2.y);
        const float hi0f = __uint_as_float(hh << 16);
        const float hi1f = __uint_as_float(hh & 0xFFFF0000u);
        const unsigned hl  = cvt_pk_bf16(h2.x - hi0f, h2.y - hi1f);

        const int buf = t & 1;
        *(unsigned*)&lds_h[buf][0][n][u0] = hh;   // u0 even -> 4B aligned
        *(unsigned*)&lds_h[buf][1][n][u0] = hl;

        __syncthreads();

        // ---- B frags for next step: units 8q..8q+7 of batch n ----
        Bh.q4 = *(const u32x4*)&lds_h[buf][0][n][8 * q];
        Bl.q4 = *(const u32x4*)&lds_h[buf][1][n][8 * q];

        xc0 = xn0; xc1 = xn1; xc2 = xn2;
    }

    // ---- epilogue (wave 0): h(511) is in lds buf 1 ----
    if (w == 0) {
        Frag Hh, Hl;
        Hh.q4 = *(const u32x4*)&lds_h[1][0][n][8 * q];
        Hl.q4 = *(const u32x4*)&lds_h[1][1][n][8 * q];
        float s0 = 0.f, s1 = 0.f;
#pragma unroll
        for (int j = 0; j < 8; ++j) {
            const float hv = bf_tof(Hh.u[j]) + bf_tof(Hl.u[j]);
            const int   u  = 8 * q + j;
            s0 = fmaf(hv, W_fc[u], s0);
            s1 = fmaf(hv, W_fc[32 + u], s1);
        }
        s0 += __shfl_xor(s0, 16, 64); s1 += __shfl_xor(s1, 16, 64);
        s0 += __shfl_xor(s0, 32, 64); s1 += __shfl_xor(s1, 32, 64);
        if (lane < 16) {
            out[(size_t)batch * 2 + 0] = s0 + b_fc[0];
            out[(size_t)batch * 2 + 1] = s1 + b_fc[1];
        }
    }
}

extern "C" void kernel_launch(void* const* d_in, const int* in_sizes, int n_in,
                              void* d_out, int out_size, void* d_ws, size_t ws_size,
                              hipStream_t stream) {
    const float* x    = (const float*)d_in[0];
    const float* W_ih = (const float*)d_in[1];
    const float* W_hh = (const float*)d_in[2];
    const float* b_ih = (const float*)d_in[3];
    const float* b_hh = (const float*)d_in[4];
    const float* W_fc = (const float*)d_in[5];
    const float* b_fc = (const float*)d_in[6];
    float* out = (float*)d_out;

    const int batch = in_sizes[0] / (kT * 3);   // 8192
    dim3 grid(batch / 16);                      // 512 blocks of 4 waves
    dim3 block(256);                            // -> 2 blocks/CU, 2 waves/SIMD
    hipLaunchKernelGGL(lstm_split2, grid, block, 0, stream,
                       x, W_ih, W_hh, b_ih, b_hh, W_fc, b_fc, out);
}